// Round 3
// baseline (90.627 us; speedup 1.0000x reference)
//
#include <hip/hip_runtime.h>
#include <cstdint>
#include <cstddef>

#define TT  2048
#define HH  1024
#define FFN 2048
#define NL  4
#define BK  64
#define BM  256
#define SK  4            // split-K for gemm2 (chunk = FFN/SK = 512)

typedef __attribute__((ext_vector_type(8))) short bf16x8;
typedef __attribute__((ext_vector_type(4))) float f32x4;

__device__ __forceinline__ unsigned short f2bf(float f) {
  unsigned u = __builtin_bit_cast(unsigned, f);
  u += 0x7FFFu + ((u >> 16) & 1u);           // RNE
  return (unsigned short)(u >> 16);
}

__device__ __forceinline__ bf16x8 pack8(f32x4 f0, f32x4 f1) {
  bf16x8 v;
  v[0] = (short)f2bf(f0[0]); v[1] = (short)f2bf(f0[1]);
  v[2] = (short)f2bf(f0[2]); v[3] = (short)f2bf(f0[3]);
  v[4] = (short)f2bf(f1[0]); v[5] = (short)f2bf(f1[1]);
  v[6] = (short)f2bf(f1[2]); v[7] = (short)f2bf(f1[3]);
  return v;
}

__device__ __forceinline__ void async16(void* lds, const void* g) {
  __builtin_amdgcn_global_load_lds(
      (const __attribute__((address_space(1))) unsigned int*)g,
      (__attribute__((address_space(3))) unsigned int*)lds, 16, 0, 0);
}

// XOR swizzle inside [rows][64 bf16] (128 B rows); involution (rule 21).
__device__ __forceinline__ int swz(int b) { return b ^ (((b >> 7) & 7) << 4); }

// ---------------------------------------------------------------- zero
__global__ void k_zero(float* __restrict__ out, int* __restrict__ cnt) {
  int i = blockIdx.x * 256 + threadIdx.x;
  f32x4 z = {0.f, 0.f, 0.f, 0.f};
  reinterpret_cast<f32x4*>(out)[i] = z;
  if (i < NL) cnt[i] = 0;
}

// ---------------------------------------------------------------- routing lists
__global__ void k_build(const int* __restrict__ sel, const float* __restrict__ rw,
                        int* __restrict__ cnt, int* __restrict__ tok,
                        float* __restrict__ wgt) {
  int t = blockIdx.x * 256 + threadIdx.x;
  if (t >= TT) return;
  int   s0 = sel[t*4+0], s1 = sel[t*4+1], s2 = sel[t*4+2], s3 = sel[t*4+3];
  float r0 = rw[t*4+0],  r1 = rw[t*4+1],  r2 = rw[t*4+2],  r3 = rw[t*4+3];
#pragma unroll
  for (int i = 0; i < NL; ++i) {
    int eid = i * 8;
    float w = 0.f; bool m = false;
    if (s0 == eid) { w += r0; m = true; }
    if (s1 == eid) { w += r1; m = true; }
    if (s2 == eid) { w += r2; m = true; }
    if (s3 == eid) { w += r3; m = true; }
    if (m) {
      int p = atomicAdd(&cnt[i], 1);
      tok[i*TT + p] = t;
      wgt[i*TT + p] = w;
    }
  }
}

// ---------------------------------------------------------------- gather
__global__ void k_gather(const float* __restrict__ hidden, const int* __restrict__ cnt,
                         const int* __restrict__ tok, unsigned short* __restrict__ X) {
  int p = blockIdx.x, e = blockIdx.y;
  if (p >= cnt[e]) return;
  int t = tok[e*TT + p];
  const f32x4* src = reinterpret_cast<const f32x4*>(hidden + (size_t)t * HH);
  f32x4 a = src[threadIdx.x*2], b = src[threadIdx.x*2 + 1];
  reinterpret_cast<bf16x8*>(X + ((size_t)e*TT + p) * HH)[threadIdx.x] = pack8(a, b);
}

// ---------------------------------------------------------------- GEMM1
// BM=256, BN=32 dual (gate+up), BK=64, 512 thr = 8 waves (4M x 2N).
// Each gup byte fetched once. 2-phase dbuf: stage(t+1) -> compute(t) ->
// write B(t+1) -> barrier.
__global__ __launch_bounds__(512) void k_gemm1(
    const unsigned short* __restrict__ X, const float* __restrict__ gup,
    const int* __restrict__ cnt, unsigned short* __restrict__ Hb) {
  int e  = blockIdx.z;
  int c  = cnt[e];
  int m0 = blockIdx.y * BM;
  if (m0 >= c) return;
  int n0 = blockIdx.x * 32;

  __shared__ alignas(16) unsigned short As[2][BM*BK];   // 2 x 32 KB
  __shared__ alignas(16) unsigned short Bs[2][64*BK];   // 2 x 8 KB (32 gate + 32 up rows)

  int tid  = threadIdx.x;
  int lane = tid & 63, wv = tid >> 6;    // 8 waves
  int lr = lane & 15,  lk = lane >> 4;
  int wm = wv >> 1,    wn = wv & 1;      // 4M x 2N

  const unsigned short* Ab = X   + (size_t)e * TT * HH;
  const float*          Gb = gup + (size_t)e * 2 * FFN * HH;

  // A staging: 32 KB = 32 x 1KB chunks, 4/wave; linear LDS dest, pre-swizzled src.
  const char* srcA[4];
  int dstA[4];
#pragma unroll
  for (int cc = 0; cc < 4; ++cc) {
    int chunk = wv * 4 + cc;
    int P = chunk * 1024 + lane * 16;
    int ar = P >> 7, ac = (P & 127) ^ ((ar & 7) << 4);
    srcA[cc] = (const char*)(Ab + (size_t)(m0 + ar) * HH) + ac;
    dstA[cc] = chunk * 1024 + lane * 16;
  }

  // B staging: 64 rows (32 gate, 32 up) x 64 k fp32 -> 32 B/thread.
  int rb  = tid >> 3;                    // 0..63
  int cbf = (tid & 7) * 8;               // float col 0..56
  int grow = (rb < 32) ? (n0 + rb) : (FFN + n0 + rb - 32);
  const float* gB = Gb + (size_t)grow * HH + cbf;
  int wb = swz(rb * 128 + cbf * 2);

  // frag ds_read offsets
  int aoff[4][2], bgo[2], buo[2];
#pragma unroll
  for (int mi = 0; mi < 4; ++mi)
#pragma unroll
    for (int kk = 0; kk < 2; ++kk)
      aoff[mi][kk] = swz((wm*64 + mi*16 + lr) * 128 + kk*64 + lk*16);
#pragma unroll
  for (int kk = 0; kk < 2; ++kk) {
    bgo[kk] = swz((wn*16 + lr) * 128 + kk*64 + lk*16);
    buo[kk] = swz((32 + wn*16 + lr) * 128 + kk*64 + lk*16);
  }

  f32x4 accg[4], accu[4];
  f32x4 z = {0.f, 0.f, 0.f, 0.f};
#pragma unroll
  for (int a = 0; a < 4; ++a) { accg[a] = z; accu[a] = z; }

  // ---- prologue: stage tile 0
#pragma unroll
  for (int cc = 0; cc < 4; ++cc) async16((char*)As[0] + dstA[cc], srcA[cc]);
  {
    f32x4 b0 = *(const f32x4*)(gB);
    f32x4 b1 = *(const f32x4*)(gB + 4);
    *(bf16x8*)((char*)Bs[0] + wb) = pack8(b0, b1);
  }
  __syncthreads();

  const int nt = HH / BK;   // 16
  int cur = 0;
  for (int t = 0; t < nt; ++t) {
    bool pre = (t + 1 < nt);
    f32x4 b0, b1;
    if (pre) {
      int k0 = (t + 1) * BK;
#pragma unroll
      for (int cc = 0; cc < 4; ++cc)
        async16((char*)As[cur^1] + dstA[cc], srcA[cc] + k0*2);
      b0 = *(const f32x4*)(gB + k0);
      b1 = *(const f32x4*)(gB + k0 + 4);
    }
    const char* Asc = (const char*)As[cur];
    const char* Bsc = (const char*)Bs[cur];
#pragma unroll
    for (int kk = 0; kk < 2; ++kk) {
      bf16x8 bg = *(const bf16x8*)(Bsc + bgo[kk]);
      bf16x8 bu = *(const bf16x8*)(Bsc + buo[kk]);
#pragma unroll
      for (int mi = 0; mi < 4; ++mi) {
        bf16x8 a = *(const bf16x8*)(Asc + aoff[mi][kk]);
        accg[mi] = __builtin_amdgcn_mfma_f32_16x16x32_bf16(a, bg, accg[mi], 0, 0, 0);
        accu[mi] = __builtin_amdgcn_mfma_f32_16x16x32_bf16(a, bu, accu[mi], 0, 0, 0);
      }
    }
    if (pre) {
      *(bf16x8*)((char*)Bs[cur^1] + wb) = pack8(b0, b1);
      __syncthreads();
    }
    cur ^= 1;
  }

  // ---- epilogue: silu(gate)*up -> bf16 Hb
#pragma unroll
  for (int mi = 0; mi < 4; ++mi)
#pragma unroll
    for (int j = 0; j < 4; ++j) {
      int p = m0 + wm*64 + mi*16 + lk*4 + j;
      if (p < c) {
        float gv = accg[mi][j];
        float hv = (gv / (1.f + __expf(-gv))) * accu[mi][j];
        int col = n0 + wn*16 + lr;
        Hb[((size_t)e * TT + p) * FFN + col] = f2bf(hv);
      }
    }
}

// ---------------------------------------------------------------- GEMM2
// out += w * (h @ down^T); BM=256, BN=64, BK=64, SK=4, 8 waves (4M x 2N).
__global__ __launch_bounds__(512) void k_gemm2(
    const unsigned short* __restrict__ Hb, const float* __restrict__ down,
    const int* __restrict__ cnt, const int* __restrict__ tok,
    const float* __restrict__ wgt, float* __restrict__ out) {
  int zz = blockIdx.z;
  int sk = zz & (SK - 1);
  int e  = zz >> 2;
  int c  = cnt[e];
  int m0 = blockIdx.y * BM;
  if (m0 >= c) return;
  int n0 = blockIdx.x * 64;
  int kbase = sk * (FFN / SK);

  __shared__ alignas(16) unsigned short As[2][BM*BK];   // 2 x 32 KB
  __shared__ alignas(16) unsigned short Bs[2][64*BK];   // 2 x 8 KB

  int tid  = threadIdx.x;
  int lane = tid & 63, wv = tid >> 6;
  int lr = lane & 15,  lk = lane >> 4;
  int wm = wv >> 1,    wn = wv & 1;

  const unsigned short* Ab = Hb   + (size_t)e * TT * FFN;
  const float*          Db = down + (size_t)e * HH * FFN;

  const char* srcA[4];
  int dstA[4];
#pragma unroll
  for (int cc = 0; cc < 4; ++cc) {
    int chunk = wv * 4 + cc;
    int P = chunk * 1024 + lane * 16;
    int ar = P >> 7, ac = (P & 127) ^ ((ar & 7) << 4);
    srcA[cc] = (const char*)(Ab + (size_t)(m0 + ar) * FFN + kbase) + ac;
    dstA[cc] = chunk * 1024 + lane * 16;
  }

  int rb  = tid >> 3;
  int cbf = (tid & 7) * 8;
  const float* gB = Db + (size_t)(n0 + rb) * FFN + kbase + cbf;
  int wb = swz(rb * 128 + cbf * 2);

  int aoff[4][2], boff[2][2];
#pragma unroll
  for (int mi = 0; mi < 4; ++mi)
#pragma unroll
    for (int kk = 0; kk < 2; ++kk)
      aoff[mi][kk] = swz((wm*64 + mi*16 + lr) * 128 + kk*64 + lk*16);
#pragma unroll
  for (int ni = 0; ni < 2; ++ni)
#pragma unroll
    for (int kk = 0; kk < 2; ++kk)
      boff[ni][kk] = swz((wn*32 + ni*16 + lr) * 128 + kk*64 + lk*16);

  f32x4 acc[4][2];
  f32x4 z = {0.f, 0.f, 0.f, 0.f};
#pragma unroll
  for (int a = 0; a < 4; ++a)
#pragma unroll
    for (int b = 0; b < 2; ++b) acc[a][b] = z;

#pragma unroll
  for (int cc = 0; cc < 4; ++cc) async16((char*)As[0] + dstA[cc], srcA[cc]);
  {
    f32x4 b0 = *(const f32x4*)(gB);
    f32x4 b1 = *(const f32x4*)(gB + 4);
    *(bf16x8*)((char*)Bs[0] + wb) = pack8(b0, b1);
  }
  __syncthreads();

  const int nt = (FFN / SK) / BK;   // 8
  int cur = 0;
  for (int t = 0; t < nt; ++t) {
    bool pre = (t + 1 < nt);
    f32x4 b0, b1;
    if (pre) {
      int k0 = (t + 1) * BK;
#pragma unroll
      for (int cc = 0; cc < 4; ++cc)
        async16((char*)As[cur^1] + dstA[cc], srcA[cc] + k0*2);
      b0 = *(const f32x4*)(gB + k0);
      b1 = *(const f32x4*)(gB + k0 + 4);
    }
    const char* Asc = (const char*)As[cur];
    const char* Bsc = (const char*)Bs[cur];
#pragma unroll
    for (int kk = 0; kk < 2; ++kk) {
      bf16x8 bf0 = *(const bf16x8*)(Bsc + boff[0][kk]);
      bf16x8 bf1 = *(const bf16x8*)(Bsc + boff[1][kk]);
#pragma unroll
      for (int mi = 0; mi < 4; ++mi) {
        bf16x8 a = *(const bf16x8*)(Asc + aoff[mi][kk]);
        acc[mi][0] = __builtin_amdgcn_mfma_f32_16x16x32_bf16(a, bf0, acc[mi][0], 0, 0, 0);
        acc[mi][1] = __builtin_amdgcn_mfma_f32_16x16x32_bf16(a, bf1, acc[mi][1], 0, 0, 0);
      }
    }
    if (pre) {
      *(bf16x8*)((char*)Bs[cur^1] + wb) = pack8(b0, b1);
      __syncthreads();
    }
    cur ^= 1;
  }

#pragma unroll
  for (int mi = 0; mi < 4; ++mi)
#pragma unroll
    for (int ni = 0; ni < 2; ++ni)
#pragma unroll
      for (int j = 0; j < 4; ++j) {
        int p = m0 + wm*64 + mi*16 + lk*4 + j;
        if (p < c) {
          int   t = tok[e*TT + p];
          float w = wgt[e*TT + p];
          int col = n0 + wn*32 + ni*16 + lr;
          atomicAdd(&out[(size_t)t * HH + col], w * acc[mi][ni][j]);
        }
      }
}

// ---------------------------------------------------------------- launch
extern "C" void kernel_launch(void* const* d_in, const int* in_sizes, int n_in,
                              void* d_out, int out_size, void* d_ws, size_t ws_size,
                              hipStream_t stream) {
  const float* hidden = (const float*)d_in[0];
  const int*   sel    = (const int*)d_in[1];
  const float* rw     = (const float*)d_in[2];
  const float* gup    = (const float*)d_in[3];
  const float* dwn    = (const float*)d_in[4];
  float* out = (float*)d_out;

  char* ws = (char*)d_ws;
  int*            cnt = (int*)ws;
  int*            tok = (int*)(ws + 1024);
  float*          wgt = (float*)(ws + 1024 + NL*TT*4);
  unsigned short* X   = (unsigned short*)(ws + 66560);
  unsigned short* Hb  = (unsigned short*)(ws + 66560 + (size_t)NL*TT*HH*2);

  k_zero  <<<2048, 256, 0, stream>>>(out, cnt);
  k_build <<<8,    256, 0, stream>>>(sel, rw, cnt, tok, wgt);
  k_gather<<<dim3(TT, NL), 128, 0, stream>>>(hidden, cnt, tok, X);
  k_gemm1 <<<dim3(FFN/32, TT/BM, NL),    512, 0, stream>>>(X, gup, cnt, Hb);
  k_gemm2 <<<dim3(HH/64, TT/BM, NL*SK), 512, 0, stream>>>(Hb, dwn, cnt, tok, wgt, out);
}

// Round 4
// 71.380 us; speedup vs baseline: 1.2696x; 1.2696x over previous
//
#include <hip/hip_runtime.h>
#include <cstdint>
#include <cstddef>

#define TT  2048
#define HH  1024
#define FFN 2048
#define NL  4
#define BK  64
#define BM  256
#define SK  4            // split-K for gemm2 (chunk = FFN/SK = 512)

typedef __attribute__((ext_vector_type(8))) short bf16x8;
typedef __attribute__((ext_vector_type(4))) float f32x4;

__device__ __forceinline__ unsigned short f2bf(float f) {
  unsigned u = __builtin_bit_cast(unsigned, f);
  u += 0x7FFFu + ((u >> 16) & 1u);           // RNE
  return (unsigned short)(u >> 16);
}

__device__ __forceinline__ bf16x8 pack8(f32x4 f0, f32x4 f1) {
  bf16x8 v;
  v[0] = (short)f2bf(f0[0]); v[1] = (short)f2bf(f0[1]);
  v[2] = (short)f2bf(f0[2]); v[3] = (short)f2bf(f0[3]);
  v[4] = (short)f2bf(f1[0]); v[5] = (short)f2bf(f1[1]);
  v[6] = (short)f2bf(f1[2]); v[7] = (short)f2bf(f1[3]);
  return v;
}

__device__ __forceinline__ void async16(void* lds, const void* g) {
  __builtin_amdgcn_global_load_lds(
      (const __attribute__((address_space(1))) unsigned int*)g,
      (__attribute__((address_space(3))) unsigned int*)lds, 16, 0, 0);
}

// XOR swizzle inside [rows][64 bf16] (128 B rows); involution (rule 21).
__device__ __forceinline__ int swz(int b) { return b ^ (((b >> 7) & 7) << 4); }

// ---------------------------------------------------------------- zero
__global__ void k_zero(float* __restrict__ out, int* __restrict__ cnt) {
  int i = blockIdx.x * 256 + threadIdx.x;
  f32x4 z = {0.f, 0.f, 0.f, 0.f};
  reinterpret_cast<f32x4*>(out)[i] = z;
  if (i < NL) cnt[i] = 0;
}

// ---------------------------------------------------------------- routing lists
__global__ void k_build(const int* __restrict__ sel, const float* __restrict__ rw,
                        int* __restrict__ cnt, int* __restrict__ tok,
                        float* __restrict__ wgt) {
  int t = blockIdx.x * 256 + threadIdx.x;
  if (t >= TT) return;
  int   s0 = sel[t*4+0], s1 = sel[t*4+1], s2 = sel[t*4+2], s3 = sel[t*4+3];
  float r0 = rw[t*4+0],  r1 = rw[t*4+1],  r2 = rw[t*4+2],  r3 = rw[t*4+3];
#pragma unroll
  for (int i = 0; i < NL; ++i) {
    int eid = i * 8;
    float w = 0.f; bool m = false;
    if (s0 == eid) { w += r0; m = true; }
    if (s1 == eid) { w += r1; m = true; }
    if (s2 == eid) { w += r2; m = true; }
    if (s3 == eid) { w += r3; m = true; }
    if (m) {
      int p = atomicAdd(&cnt[i], 1);
      tok[i*TT + p] = t;
      wgt[i*TT + p] = w;
    }
  }
}

// ---------------------------------------------------------------- gather
__global__ void k_gather(const float* __restrict__ hidden, const int* __restrict__ cnt,
                         const int* __restrict__ tok, unsigned short* __restrict__ X) {
  int p = blockIdx.x, e = blockIdx.y;
  if (p >= cnt[e]) return;
  int t = tok[e*TT + p];
  const f32x4* src = reinterpret_cast<const f32x4*>(hidden + (size_t)t * HH);
  f32x4 a = src[threadIdx.x*2], b = src[threadIdx.x*2 + 1];
  reinterpret_cast<bf16x8*>(X + ((size_t)e*TT + p) * HH)[threadIdx.x] = pack8(a, b);
}

// ---------------------------------------------------------------- GEMM1
// 256 blocks (1/CU): bid -> (e, n0). BM=256, BN=32 dual (gate+up), BK=64,
// 512 thr = 8 waves (4M x 2N). Each gup byte fetched once. 2-phase dbuf.
// m0-loop inside (normally 1 iter since c ~= 256).
__global__ __launch_bounds__(512) void k_gemm1(
    const unsigned short* __restrict__ X, const float* __restrict__ gup,
    const int* __restrict__ cnt, unsigned short* __restrict__ Hb) {
  int bid = blockIdx.x;
  int e   = bid >> 6;
  int n0  = (bid & 63) * 32;
  int c   = cnt[e];

  __shared__ alignas(16) unsigned short As[2][BM*BK];   // 2 x 32 KB
  __shared__ alignas(16) unsigned short Bs[2][64*BK];   // 2 x 8 KB

  int tid  = threadIdx.x;
  int lane = tid & 63, wv = tid >> 6;
  int lr = lane & 15,  lk = lane >> 4;
  int wm = wv >> 1,    wn = wv & 1;

  const unsigned short* Ab = X   + (size_t)e * TT * HH;
  const float*          Gb = gup + (size_t)e * 2 * FFN * HH;

  // A staging geometry (row/col within tile; m0 added per iteration)
  int arow[4], acol[4], dstA[4];
#pragma unroll
  for (int cc = 0; cc < 4; ++cc) {
    int chunk = wv * 4 + cc;
    int P = chunk * 1024 + lane * 16;
    arow[cc] = P >> 7;
    acol[cc] = (P & 127) ^ ((arow[cc] & 7) << 4);
    dstA[cc] = chunk * 1024 + lane * 16;
  }

  // B staging: 64 rows (32 gate, 32 up) x 64 k fp32 -> 32 B/thread.
  int rb  = tid >> 3;
  int cbf = (tid & 7) * 8;
  int grow = (rb < 32) ? (n0 + rb) : (FFN + n0 + rb - 32);
  const float* gB = Gb + (size_t)grow * HH + cbf;
  int wb = swz(rb * 128 + cbf * 2);

  int aoff[4][2], bgo[2], buo[2];
#pragma unroll
  for (int mi = 0; mi < 4; ++mi)
#pragma unroll
    for (int kk = 0; kk < 2; ++kk)
      aoff[mi][kk] = swz((wm*64 + mi*16 + lr) * 128 + kk*64 + lk*16);
#pragma unroll
  for (int kk = 0; kk < 2; ++kk) {
    bgo[kk] = swz((wn*16 + lr) * 128 + kk*64 + lk*16);
    buo[kk] = swz((32 + wn*16 + lr) * 128 + kk*64 + lk*16);
  }

  for (int m0 = 0; m0 < c; m0 += BM) {
    __syncthreads();   // cross-iteration buffer reuse guard (no-op 1st iter)

    const char* srcA[4];
#pragma unroll
    for (int cc = 0; cc < 4; ++cc)
      srcA[cc] = (const char*)(Ab + (size_t)(m0 + arow[cc]) * HH) + acol[cc];

    f32x4 accg[4], accu[4];
    f32x4 z = {0.f, 0.f, 0.f, 0.f};
#pragma unroll
    for (int a = 0; a < 4; ++a) { accg[a] = z; accu[a] = z; }

    // prologue: stage tile 0
#pragma unroll
    for (int cc = 0; cc < 4; ++cc) async16((char*)As[0] + dstA[cc], srcA[cc]);
    {
      f32x4 b0 = *(const f32x4*)(gB);
      f32x4 b1 = *(const f32x4*)(gB + 4);
      *(bf16x8*)((char*)Bs[0] + wb) = pack8(b0, b1);
    }
    __syncthreads();

    const int nt = HH / BK;   // 16
    int cur = 0;
    for (int t = 0; t < nt; ++t) {
      bool pre = (t + 1 < nt);
      f32x4 b0, b1;
      if (pre) {
        int k0 = (t + 1) * BK;
#pragma unroll
        for (int cc = 0; cc < 4; ++cc)
          async16((char*)As[cur^1] + dstA[cc], srcA[cc] + k0*2);
        b0 = *(const f32x4*)(gB + k0);
        b1 = *(const f32x4*)(gB + k0 + 4);
      }
      const char* Asc = (const char*)As[cur];
      const char* Bsc = (const char*)Bs[cur];
#pragma unroll
      for (int kk = 0; kk < 2; ++kk) {
        bf16x8 bg = *(const bf16x8*)(Bsc + bgo[kk]);
        bf16x8 bu = *(const bf16x8*)(Bsc + buo[kk]);
#pragma unroll
        for (int mi = 0; mi < 4; ++mi) {
          bf16x8 a = *(const bf16x8*)(Asc + aoff[mi][kk]);
          accg[mi] = __builtin_amdgcn_mfma_f32_16x16x32_bf16(a, bg, accg[mi], 0, 0, 0);
          accu[mi] = __builtin_amdgcn_mfma_f32_16x16x32_bf16(a, bu, accu[mi], 0, 0, 0);
        }
      }
      if (pre) {
        *(bf16x8*)((char*)Bs[cur^1] + wb) = pack8(b0, b1);
        __syncthreads();
      }
      cur ^= 1;
    }

    // epilogue: silu(gate)*up -> bf16 Hb
#pragma unroll
    for (int mi = 0; mi < 4; ++mi)
#pragma unroll
      for (int j = 0; j < 4; ++j) {
        int p = m0 + wm*64 + mi*16 + lk*4 + j;
        if (p < c) {
          float gv = accg[mi][j];
          float hv = (gv / (1.f + __expf(-gv))) * accu[mi][j];
          int col = n0 + wn*16 + lr;
          Hb[((size_t)e * TT + p) * FFN + col] = f2bf(hv);
        }
      }
  }
}

// ---------------------------------------------------------------- GEMM2
// 256 blocks (1/CU): bid -> (e, sk, n0). out += w * (h @ down^T);
// BM=256, BN=64, BK=64, SK=4, 8 waves (4M x 2N).
__global__ __launch_bounds__(512) void k_gemm2(
    const unsigned short* __restrict__ Hb, const float* __restrict__ down,
    const int* __restrict__ cnt, const int* __restrict__ tok,
    const float* __restrict__ wgt, float* __restrict__ out) {
  int bid = blockIdx.x;
  int e   = bid >> 6;
  int sk  = (bid >> 4) & 3;
  int n0  = (bid & 15) * 64;
  int c   = cnt[e];
  int kbase = sk * (FFN / SK);

  __shared__ alignas(16) unsigned short As[2][BM*BK];
  __shared__ alignas(16) unsigned short Bs[2][64*BK];

  int tid  = threadIdx.x;
  int lane = tid & 63, wv = tid >> 6;
  int lr = lane & 15,  lk = lane >> 4;
  int wm = wv >> 1,    wn = wv & 1;

  const unsigned short* Ab = Hb   + (size_t)e * TT * FFN;
  const float*          Db = down + (size_t)e * HH * FFN;

  int arow[4], acol[4], dstA[4];
#pragma unroll
  for (int cc = 0; cc < 4; ++cc) {
    int chunk = wv * 4 + cc;
    int P = chunk * 1024 + lane * 16;
    arow[cc] = P >> 7;
    acol[cc] = (P & 127) ^ ((arow[cc] & 7) << 4);
    dstA[cc] = chunk * 1024 + lane * 16;
  }

  int rb  = tid >> 3;
  int cbf = (tid & 7) * 8;
  const float* gB = Db + (size_t)(n0 + rb) * FFN + kbase + cbf;
  int wb = swz(rb * 128 + cbf * 2);

  int aoff[4][2], boff[2][2];
#pragma unroll
  for (int mi = 0; mi < 4; ++mi)
#pragma unroll
    for (int kk = 0; kk < 2; ++kk)
      aoff[mi][kk] = swz((wm*64 + mi*16 + lr) * 128 + kk*64 + lk*16);
#pragma unroll
  for (int ni = 0; ni < 2; ++ni)
#pragma unroll
    for (int kk = 0; kk < 2; ++kk)
      boff[ni][kk] = swz((wn*32 + ni*16 + lr) * 128 + kk*64 + lk*16);

  for (int m0 = 0; m0 < c; m0 += BM) {
    __syncthreads();

    const char* srcA[4];
#pragma unroll
    for (int cc = 0; cc < 4; ++cc)
      srcA[cc] = (const char*)(Ab + (size_t)(m0 + arow[cc]) * FFN + kbase) + acol[cc];

    f32x4 acc[4][2];
    f32x4 z = {0.f, 0.f, 0.f, 0.f};
#pragma unroll
    for (int a = 0; a < 4; ++a)
#pragma unroll
      for (int b = 0; b < 2; ++b) acc[a][b] = z;

#pragma unroll
    for (int cc = 0; cc < 4; ++cc) async16((char*)As[0] + dstA[cc], srcA[cc]);
    {
      f32x4 b0 = *(const f32x4*)(gB);
      f32x4 b1 = *(const f32x4*)(gB + 4);
      *(bf16x8*)((char*)Bs[0] + wb) = pack8(b0, b1);
    }
    __syncthreads();

    const int nt = (FFN / SK) / BK;   // 8
    int cur = 0;
    for (int t = 0; t < nt; ++t) {
      bool pre = (t + 1 < nt);
      f32x4 b0, b1;
      if (pre) {
        int k0 = (t + 1) * BK;
#pragma unroll
        for (int cc = 0; cc < 4; ++cc)
          async16((char*)As[cur^1] + dstA[cc], srcA[cc] + k0*2);
        b0 = *(const f32x4*)(gB + k0);
        b1 = *(const f32x4*)(gB + k0 + 4);
      }
      const char* Asc = (const char*)As[cur];
      const char* Bsc = (const char*)Bs[cur];
#pragma unroll
      for (int kk = 0; kk < 2; ++kk) {
        bf16x8 bf0 = *(const bf16x8*)(Bsc + boff[0][kk]);
        bf16x8 bf1 = *(const bf16x8*)(Bsc + boff[1][kk]);
#pragma unroll
        for (int mi = 0; mi < 4; ++mi) {
          bf16x8 a = *(const bf16x8*)(Asc + aoff[mi][kk]);
          acc[mi][0] = __builtin_amdgcn_mfma_f32_16x16x32_bf16(a, bf0, acc[mi][0], 0, 0, 0);
          acc[mi][1] = __builtin_amdgcn_mfma_f32_16x16x32_bf16(a, bf1, acc[mi][1], 0, 0, 0);
        }
      }
      if (pre) {
        *(bf16x8*)((char*)Bs[cur^1] + wb) = pack8(b0, b1);
        __syncthreads();
      }
      cur ^= 1;
    }

#pragma unroll
    for (int mi = 0; mi < 4; ++mi)
#pragma unroll
      for (int ni = 0; ni < 2; ++ni)
#pragma unroll
        for (int j = 0; j < 4; ++j) {
          int p = m0 + wm*64 + mi*16 + lk*4 + j;
          if (p < c) {
            int   t = tok[e*TT + p];
            float w = wgt[e*TT + p];
            int col = n0 + wn*32 + ni*16 + lr;
            atomicAdd(&out[(size_t)t * HH + col], w * acc[mi][ni][j]);
          }
        }
  }
}

// ---------------------------------------------------------------- launch
extern "C" void kernel_launch(void* const* d_in, const int* in_sizes, int n_in,
                              void* d_out, int out_size, void* d_ws, size_t ws_size,
                              hipStream_t stream) {
  const float* hidden = (const float*)d_in[0];
  const int*   sel    = (const int*)d_in[1];
  const float* rw     = (const float*)d_in[2];
  const float* gup    = (const float*)d_in[3];
  const float* dwn    = (const float*)d_in[4];
  float* out = (float*)d_out;

  char* ws = (char*)d_ws;
  int*            cnt = (int*)ws;
  int*            tok = (int*)(ws + 1024);
  float*          wgt = (float*)(ws + 1024 + NL*TT*4);
  unsigned short* X   = (unsigned short*)(ws + 66560);
  unsigned short* Hb  = (unsigned short*)(ws + 66560 + (size_t)NL*TT*HH*2);

  k_zero  <<<2048, 256, 0, stream>>>(out, cnt);
  k_build <<<8,    256, 0, stream>>>(sel, rw, cnt, tok, wgt);
  k_gather<<<dim3(TT, NL), 128, 0, stream>>>(hidden, cnt, tok, X);
  k_gemm1 <<<256, 512, 0, stream>>>(X, gup, cnt, Hb);
  k_gemm2 <<<256, 512, 0, stream>>>(Hb, dwn, cnt, tok, wgt, out);
}